// Round 13
// baseline (349.238 us; speedup 1.0000x reference)
//
#include <hip/hip_runtime.h>
#include <hip/hip_bf16.h>
#include <math.h>

typedef __attribute__((ext_vector_type(8)))  _Float16 f16x8;
typedef __attribute__((ext_vector_type(2)))  __fp16   fp16v2;
typedef __attribute__((ext_vector_type(16))) float    f32x16;

// ---------------------------------------------------------------------------
// GATr forward on MI355X. B=4, N=4096, H=5, BLK=3, INV=32, 16 blades.
// Attention: fp16 MFMA, exp2 softmax, pi-permuted V (local P-pack),
// XCD<->batch pinning, and 2 Q-tiles PER WAVE so each K/V line feeds 64
// query rows (halves cache-line request traffic, doubles per-wave ILP).
// Block = 8 waves = one 64-row Q-pair x 8 key-splits; intra-block merge.
// ---------------------------------------------------------------------------

namespace ga {
constexpr int MASKS[16] = {0,1,2,4,8,3,5,6,9,10,12,7,11,13,14,15};
constexpr int popc4(int x){ return (x&1)+((x>>1)&1)+((x>>2)&1)+((x>>3)&1); }
constexpr int idx_of(int m){ int r=-1; for(int i=0;i<16;i++) if(MASKS[i]==m) r=i; return r; }
struct GPTab {
  int cnt[16];
  signed char ii[16][16];
  signed char jj[16][16];
  float ss[16][16];
};
constexpr GPTab make_gptab(){
  GPTab t{};
  for(int i=0;i<16;i++) for(int j=0;j<16;j++){
    int a=MASKS[i], b=MASKS[j];
    if((a&b&1)!=0) continue;           // e0^2 = 0 kills the term
    int sw=0;
    for(int bi=0;bi<4;bi++) if((b>>bi)&1) sw += popc4(a>>(bi+1));
    int k = idx_of(a^b);
    int c = t.cnt[k];
    t.ii[k][c]=(signed char)i; t.jj[k][c]=(signed char)j;
    t.ss[k][c]=(sw&1)? -1.0f : 1.0f;
    t.cnt[k]=c+1;
  }
  return t;
}
} // namespace ga

__device__ const ga::GPTab GPT = ga::make_gptab();
__constant__ int GRADE16[16] = {0,1,1,1,1,2,2,2,2,2,2,3,3,3,3,4};
__constant__ int CPOS16[16] = {0,-1,1,2,3,-1,-1,4,-1,5,6,-1,-1,-1,7,-1};

#define NTOK 16384   // B*N
#define NSEQ 4096
#define NB 4
#define QP 64        // q/k row stride (40 real feats + pads; 128B rows)
#define VTROWS 80    // v tile rows (feats)
#define NW 8         // waves per attention block (key-split factor)
#define THR2 11.54f  // defer-max threshold in log2 domain (= 8 nats)

// --------------------------------------------------------------------------
// K1: h[token][o][c] = equi_linear(mv, w_in); mv sparse.
// --------------------------------------------------------------------------
__global__ __launch_bounds__(256) void k_init_h(
    const float* __restrict__ x, const float* __restrict__ w_in,
    float* __restrict__ h)
{
  int gid = blockIdx.x*256 + threadIdx.x;      // token*5 + o
  if (gid >= NTOK*5) return;
  int o = gid % 5, token = gid / 5;
  const float* xt = x + (size_t)token*35;
  const float* w0 = w_in + o*32;               // grade-0 block, row o
  float s = w0[0];                             // mv[0][0] = 1.0
  #pragma unroll
  for (int i=1;i<32;i++) s += w0[i]*xt[i];
  float w2c = w_in[2*160 + o*32 + 0];          // grade-2, input channel 0
  float* ht = h + (size_t)token*80 + o*16;
  #pragma unroll
  for (int c=0;c<16;c++) ht[c] = 0.f;
  ht[0] = s;
  ht[5] = w2c*xt[32];
  ht[6] = w2c*xt[33];
  ht[8] = w2c*xt[34];
}

// --------------------------------------------------------------------------
// K2: fused equi_layernorm + q,k,v equi_linear -> fp16 staging.
// q/k: [token][64]; q pre-scaled by scale*log2(e).
// v: TILE-MAJOR vt[b][tile][feat(80)][col], key->col permuted (pi).
// --------------------------------------------------------------------------
__global__ __launch_bounds__(256) void k_ln_qkv(
    const float* __restrict__ h,
    const float* __restrict__ wq, const float* __restrict__ wk,
    const float* __restrict__ wv,
    _Float16* __restrict__ qf, _Float16* __restrict__ kf,
    _Float16* __restrict__ vf)
{
  int tid = threadIdx.x;
  int c   = tid & 15;
  int token = blockIdx.x*16 + (tid>>4);
  int b = token >> 12;          // /4096
  int n = token & 4095;
  int vt_tile = b*128 + (n>>5);
  int nn = n & 31;
  int t  = (nn>>2)&3;
  int t2 = ((t<<1)|(t>>1))&3;             // 0,3 fixed; 1<->2
  int vt_col = (nn&3) | (t2<<2) | (nn&16);
  const float* ht = h + (size_t)token*80;
  float hv[5];
  #pragma unroll
  for (int i=0;i<5;i++) hv[i] = ht[i*16 + c];
  bool inner = (0x469D >> c) & 1;
  float part = 0.f;
  if (inner) {
    #pragma unroll
    for (int i=0;i<5;i++) part += hv[i]*hv[i];
  }
  part += __shfl_xor(part, 1);
  part += __shfl_xor(part, 2);
  part += __shfl_xor(part, 4);
  part += __shfl_xor(part, 8);
  float denom = sqrtf(part*(1.f/80.f) + 1e-6f);
  float rinv = 1.f/denom;
  float rln[5];
  #pragma unroll
  for (int i=0;i<5;i++) rln[i] = hv[i]*rinv;

  int g = GRADE16[c];
  int cp = CPOS16[c];
  const float scaleq = 0.16129820906f;   // (1/sqrt(80)) * log2(e)
  #pragma unroll
  for (int o=0;o<5;o++) {
    const float* wqr = wq + g*25 + o*5;
    const float* wkr = wk + g*25 + o*5;
    const float* wvr = wv + g*25 + o*5;
    float aq=0.f, ak=0.f, av=0.f;
    #pragma unroll
    for (int i=0;i<5;i++) {
      aq += rln[i]*wqr[i];
      ak += rln[i]*wkr[i];
      av += rln[i]*wvr[i];
    }
    vf[((size_t)vt_tile*VTROWS + o*16 + c)*32 + vt_col] = (_Float16)av;
    if (inner) {
      size_t qo = (size_t)token*QP + o*8 + cp;
      qf[qo] = (_Float16)(aq*scaleq);
      kf[qo] = (_Float16)ak;
    }
  }
  if (c < 8) {
    size_t po = (size_t)token*QP + 40 + c;
    qf[po] = (_Float16)0.f;
    kf[po] = (_Float16)0.f;
  }
}

// --------------------------------------------------------------------------
// K3: fp16 MFMA flash attention. Block = 512 thr = 8 waves = one 64-row
// Q-pair; wave w covers keys [w*512, (w+1)*512) = 16 tiles, computing BOTH
// 32-row Q-tiles of the pair against each K/V tile (2x line-traffic reuse).
// XCD pinning: bid%8 -> XCD; batch = xcd&3. pi-permuted V -> local P pack.
// K depth-1 register prefetch; V loaded early each iteration.
// --------------------------------------------------------------------------
__global__ __launch_bounds__(512, 2) void k_attn_mfma(
    const _Float16* __restrict__ qf, const _Float16* __restrict__ kf,
    const _Float16* __restrict__ vf,
    const float* __restrict__ wo, float* __restrict__ h)
{
  __shared__ __align__(16) float satt[64][80];
  __shared__ __align__(16) float ldsbA[NW][32];
  __shared__ __align__(16) float ldsbB[NW][32];
  __shared__ __align__(16) float sM[NW][64];
  __shared__ __align__(16) float sL[NW][64];
  __shared__ __align__(16) float sMax[64];
  __shared__ __align__(16) float sInv[64];
  __shared__ float sWo[125];
  int tid = threadIdx.x;
  int w  = tid >> 6;
  int ln = tid & 31;
  int hf = (tid >> 5) & 1;
  // XCD pinning
  int bid = blockIdx.x;
  int xcd = bid & 7;
  int b   = xcd & 3;
  int pair = (xcd >> 2)*32 + (bid >> 3);   // 0..63
  int rowbaseA = b*NSEQ + pair*64;
  int rowbaseB = rowbaseA + 32;

  for (int i=tid; i<125; i+=512) sWo[i] = wo[i];
  for (int i=tid; i<5120; i+=512) ((float*)satt)[i] = 0.f;

  // Q frags (B operand): j=lane&31=qrow, k=(lane>>5)*8+e
  const _Float16* qpA = qf + (size_t)(rowbaseA + ln)*QP + hf*8;
  f16x8 qA0 = *(const f16x8*)(qpA);
  f16x8 qA1 = *(const f16x8*)(qpA + 16);
  f16x8 qA2 = *(const f16x8*)(qpA + 32);
  const _Float16* qpB = qf + (size_t)(rowbaseB + ln)*QP + hf*8;
  f16x8 qB0 = *(const f16x8*)(qpB);
  f16x8 qB1 = *(const f16x8*)(qpB + 16);
  f16x8 qB2 = *(const f16x8*)(qpB + 32);

  f32x16 accA0, accA1, accA2, accB0, accB1, accB2;
  #pragma unroll
  for (int r=0;r<16;r++){
    accA0[r]=0.f; accA1[r]=0.f; accA2[r]=0.f;
    accB0[r]=0.f; accB1[r]=0.f; accB2[r]=0.f;
  }
  float mA = -1e30f, lsumA = 0.f;
  float mB = -1e30f, lsumB = 0.f;

  // per-lane offsets into a V tile (tile-major: [feat(80)][32 perm cols])
  int voff0 = (     ln)*32 + hf*8;
  int voff1 = (32 + ln)*32 + hf*8;
  int voff2 = (64 + (ln&15))*32 + hf*8;

  int kbeg = w*(NSEQ/NW), kend = kbeg + NSEQ/NW;
  const _Float16* kbase = kf + (size_t)(b*NSEQ + ln)*QP + hf*8;
  const _Float16* vbase = vf + (size_t)(b*128)*(VTROWS*32);

  // prologue: preload first K tile
  const _Float16* kp0 = kbase + (size_t)kbeg*QP;
  f16x8 kc0 = *(const f16x8*)(kp0);
  f16x8 kc1 = *(const f16x8*)(kp0 + 16);
  f16x8 kc2 = *(const f16x8*)(kp0 + 32);

  for (int koff=kbeg; koff<kend; koff+=32) {
    // QK^T for both Q-tiles on the shared K frags
    f32x16 SA, SB;
    #pragma unroll
    for (int r=0;r<16;r++){ SA[r]=0.f; SB[r]=0.f; }
    SA = __builtin_amdgcn_mfma_f32_32x32x16_f16(kc0, qA0, SA, 0,0,0);
    SA = __builtin_amdgcn_mfma_f32_32x32x16_f16(kc1, qA1, SA, 0,0,0);
    SA = __builtin_amdgcn_mfma_f32_32x32x16_f16(kc2, qA2, SA, 0,0,0);
    SB = __builtin_amdgcn_mfma_f32_32x32x16_f16(kc0, qB0, SB, 0,0,0);
    SB = __builtin_amdgcn_mfma_f32_32x32x16_f16(kc1, qB1, SB, 0,0,0);
    SB = __builtin_amdgcn_mfma_f32_32x32x16_f16(kc2, qB2, SB, 0,0,0);

    // prefetch next K tile
    int knext = koff + 32; if (knext >= kend) knext = kbeg;
    const _Float16* kp = kbase + (size_t)knext*QP;
    f16x8 kn0 = *(const f16x8*)(kp);
    f16x8 kn1 = *(const f16x8*)(kp + 16);
    f16x8 kn2 = *(const f16x8*)(kp + 32);

    // V loads for current tile (issued before softmax; consumed after)
    const _Float16* vp = vbase + (size_t)(koff>>5)*(VTROWS*32);
    f16x8 vc00 = *(const f16x8*)(vp + voff0);
    f16x8 vc01 = *(const f16x8*)(vp + voff0 + 16);
    f16x8 vc10 = *(const f16x8*)(vp + voff1);
    f16x8 vc11 = *(const f16x8*)(vp + voff1 + 16);
    f16x8 vc20 = *(const f16x8*)(vp + voff2);
    f16x8 vc21 = *(const f16x8*)(vp + voff2 + 16);

    // ---- softmax tile A ----
    {
      float t01 = fmaxf(SA[0],SA[1]),   t23 = fmaxf(SA[2],SA[3]);
      float t45 = fmaxf(SA[4],SA[5]),   t67 = fmaxf(SA[6],SA[7]);
      float t89 = fmaxf(SA[8],SA[9]),   tab = fmaxf(SA[10],SA[11]);
      float tcd = fmaxf(SA[12],SA[13]), tef = fmaxf(SA[14],SA[15]);
      float u0 = fmaxf(t01,t23), u1 = fmaxf(t45,t67);
      float u2 = fmaxf(t89,tab), u3 = fmaxf(tcd,tef);
      float tmax = fmaxf(fmaxf(u0,u1), fmaxf(u2,u3));
      tmax = fmaxf(tmax, __shfl_xor(tmax, 32));
      if (!__all(tmax <= mA + THR2)) {
        float mn = fmaxf(mA, tmax);
        float f = exp2f(mA - mn);
        if (hf==0) ldsbA[w][ln] = f;
        float fv[16];
        *(float4*)&fv[0]  = *(const float4*)&ldsbA[w][ 0 + hf*4];
        *(float4*)&fv[4]  = *(const float4*)&ldsbA[w][ 8 + hf*4];
        *(float4*)&fv[8]  = *(const float4*)&ldsbA[w][16 + hf*4];
        *(float4*)&fv[12] = *(const float4*)&ldsbA[w][24 + hf*4];
        #pragma unroll
        for (int r=0;r<16;r++){ float fr=fv[r]; accA0[r]*=fr; accA1[r]*=fr; accA2[r]*=fr; }
        lsumA *= f;
        mA = mn;
      }
    }
    float pA[16];
    #pragma unroll
    for (int r=0;r<16;r++) pA[r] = exp2f(SA[r] - mA);
    {
      float s0 = (pA[0]+pA[1]) + (pA[2]+pA[3]);
      float s1 = (pA[4]+pA[5]) + (pA[6]+pA[7]);
      float s2 = (pA[8]+pA[9]) + (pA[10]+pA[11]);
      float s3 = (pA[12]+pA[13]) + (pA[14]+pA[15]);
      lsumA += (s0+s1) + (s2+s3);
    }
    union { unsigned u[4]; f16x8 v; } A0A, A1A;
    #pragma unroll
    for (int e=0;e<4;e++) {
      union { fp16v2 h2; unsigned u; } cv;
      cv.h2 = __builtin_amdgcn_cvt_pkrtz(pA[2*e], pA[2*e+1]);
      A0A.u[e] = cv.u;
    }
    #pragma unroll
    for (int e=0;e<4;e++) {
      union { fp16v2 h2; unsigned u; } cv;
      cv.h2 = __builtin_amdgcn_cvt_pkrtz(pA[8+2*e], pA[9+2*e]);
      A1A.u[e] = cv.u;
    }

    // ---- softmax tile B ----
    {
      float t01 = fmaxf(SB[0],SB[1]),   t23 = fmaxf(SB[2],SB[3]);
      float t45 = fmaxf(SB[4],SB[5]),   t67 = fmaxf(SB[6],SB[7]);
      float t89 = fmaxf(SB[8],SB[9]),   tab = fmaxf(SB[10],SB[11]);
      float tcd = fmaxf(SB[12],SB[13]), tef = fmaxf(SB[14],SB[15]);
      float u0 = fmaxf(t01,t23), u1 = fmaxf(t45,t67);
      float u2 = fmaxf(t89,tab), u3 = fmaxf(tcd,tef);
      float tmax = fmaxf(tmax = fmaxf(u0,u1), fmaxf(u2,u3));
      tmax = fmaxf(tmax, __shfl_xor(tmax, 32));
      if (!__all(tmax <= mB + THR2)) {
        float mn = fmaxf(mB, tmax);
        float f = exp2f(mB - mn);
        if (hf==0) ldsbB[w][ln] = f;
        float fv[16];
        *(float4*)&fv[0]  = *(const float4*)&ldsbB[w][ 0 + hf*4];
        *(float4*)&fv[4]  = *(const float4*)&ldsbB[w][ 8 + hf*4];
        *(float4*)&fv[8]  = *(const float4*)&ldsbB[w][16 + hf*4];
        *(float4*)&fv[12] = *(const float4*)&ldsbB[w][24 + hf*4];
        #pragma unroll
        for (int r=0;r<16;r++){ float fr=fv[r]; accB0[r]*=fr; accB1[r]*=fr; accB2[r]*=fr; }
        lsumB *= f;
        mB = mn;
      }
    }
    float pB[16];
    #pragma unroll
    for (int r=0;r<16;r++) pB[r] = exp2f(SB[r] - mB);
    {
      float s0 = (pB[0]+pB[1]) + (pB[2]+pB[3]);
      float s1 = (pB[4]+pB[5]) + (pB[6]+pB[7]);
      float s2 = (pB[8]+pB[9]) + (pB[10]+pB[11]);
      float s3 = (pB[12]+pB[13]) + (pB[14]+pB[15]);
      lsumB += (s0+s1) + (s2+s3);
    }
    union { unsigned u[4]; f16x8 v; } A0B, A1B;
    #pragma unroll
    for (int e=0;e<4;e++) {
      union { fp16v2 h2; unsigned u; } cv;
      cv.h2 = __builtin_amdgcn_cvt_pkrtz(pB[2*e], pB[2*e+1]);
      A0B.u[e] = cv.u;
    }
    #pragma unroll
    for (int e=0;e<4;e++) {
      union { fp16v2 h2; unsigned u; } cv;
      cv.h2 = __builtin_amdgcn_cvt_pkrtz(pB[8+2*e], pB[9+2*e]);
      A1B.u[e] = cv.u;
    }

    // PV for both tiles on shared V frags
    accA0 = __builtin_amdgcn_mfma_f32_32x32x16_f16(A0A.v, vc00, accA0, 0,0,0);
    accA0 = __builtin_amdgcn_mfma_f32_32x32x16_f16(A1A.v, vc01, accA0, 0,0,0);
    accA1 = __builtin_amdgcn_mfma_f32_32x32x16_f16(A0A.v, vc10, accA1, 0,0,0);
    accA1 = __builtin_amdgcn_mfma_f32_32x32x16_f16(A1A.v, vc11, accA1, 0,0,0);
    accA2 = __builtin_amdgcn_mfma_f32_32x32x16_f16(A0A.v, vc20, accA2, 0,0,0);
    accA2 = __builtin_amdgcn_mfma_f32_32x32x16_f16(A1A.v, vc21, accA2, 0,0,0);
    accB0 = __builtin_amdgcn_mfma_f32_32x32x16_f16(A0B.v, vc00, accB0, 0,0,0);
    accB0 = __builtin_amdgcn_mfma_f32_32x32x16_f16(A1B.v, vc01, accB0, 0,0,0);
    accB1 = __builtin_amdgcn_mfma_f32_32x32x16_f16(A0B.v, vc10, accB1, 0,0,0);
    accB1 = __builtin_amdgcn_mfma_f32_32x32x16_f16(A1B.v, vc11, accB1, 0,0,0);
    accB2 = __builtin_amdgcn_mfma_f32_32x32x16_f16(A0B.v, vc20, accB2, 0,0,0);
    accB2 = __builtin_amdgcn_mfma_f32_32x32x16_f16(A1B.v, vc21, accB2, 0,0,0);

    kc0 = kn0; kc1 = kn1; kc2 = kn2;
  }

  // merge per-half lsum partials
  lsumA += __shfl_xor(lsumA, 32);
  lsumB += __shfl_xor(lsumB, 32);

  // ---- cross-wave merge (64 rows) ----
  if (hf==0) {
    sM[w][ln]    = mA;  sL[w][ln]    = lsumA;
    sM[w][32+ln] = mB;  sL[w][32+ln] = lsumB;
  }
  __syncthreads();
  if (tid < 64) {
    float M = sM[0][tid];
    #pragma unroll
    for (int u=1;u<NW;u++) M = fmaxf(M, sM[u][tid]);
    float L = 0.f;
    #pragma unroll
    for (int u=0;u<NW;u++) L += exp2f(sM[u][tid] - M)*sL[u][tid];
    sMax[tid] = M;
    sInv[tid] = 1.f/L;
  }
  __syncthreads();
  // scale + accumulate into satt
  {
    float sm[16], sx[16];
    // tile A
    *(float4*)&sm[0]  = *(const float4*)&sM[w][ 0 + hf*4];
    *(float4*)&sm[4]  = *(const float4*)&sM[w][ 8 + hf*4];
    *(float4*)&sm[8]  = *(const float4*)&sM[w][16 + hf*4];
    *(float4*)&sm[12] = *(const float4*)&sM[w][24 + hf*4];
    *(float4*)&sx[0]  = *(const float4*)&sMax[ 0 + hf*4];
    *(float4*)&sx[4]  = *(const float4*)&sMax[ 8 + hf*4];
    *(float4*)&sx[8]  = *(const float4*)&sMax[16 + hf*4];
    *(float4*)&sx[12] = *(const float4*)&sMax[24 + hf*4];
    #pragma unroll
    for (int r=0;r<16;r++) {
      int row = (r&3) + 8*(r>>2) + 4*hf;
      float f = exp2f(sm[r] - sx[r]);
      atomicAdd(&satt[row][ln],    f*accA0[r]);
      atomicAdd(&satt[row][32+ln], f*accA1[r]);
      if (ln < 16) atomicAdd(&satt[row][64+ln], f*accA2[r]);
    }
    // tile B
    *(float4*)&sm[0]  = *(const float4*)&sM[w][32 +  0 + hf*4];
    *(float4*)&sm[4]  = *(const float4*)&sM[w][32 +  8 + hf*4];
    *(float4*)&sm[8]  = *(const float4*)&sM[w][32 + 16 + hf*4];
    *(float4*)&sm[12] = *(const float4*)&sM[w][32 + 24 + hf*4];
    *(float4*)&sx[0]  = *(const float4*)&sMax[32 +  0 + hf*4];
    *(float4*)&sx[4]  = *(const float4*)&sMax[32 +  8 + hf*4];
    *(float4*)&sx[8]  = *(const float4*)&sMax[32 + 16 + hf*4];
    *(float4*)&sx[12] = *(const float4*)&sMax[32 + 24 + hf*4];
    #pragma unroll
    for (int r=0;r<16;r++) {
      int row = 32 + (r&3) + 8*(r>>2) + 4*hf;
      float f = exp2f(sm[r] - sx[r]);
      atomicAdd(&satt[row][ln],    f*accB0[r]);
      atomicAdd(&satt[row][32+ln], f*accB1[r]);
      if (ln < 16) atomicAdd(&satt[row][64+ln], f*accB2[r]);
    }
  }
  __syncthreads();
  // wo-projection + residual for 64 rows
  float* hb = h + (size_t)rowbaseA*80;
  #pragma unroll
  for (int e=0;e<10;e++) {
    int flat = e*512 + tid;
    int rr = flat/80, oc = flat - rr*80;
    int o = oc>>4, c = oc&15;
    int g = GRADE16[c];
    const float* wor = sWo + g*25 + o*5;
    float a = 0.f;
    #pragma unroll
    for (int i=0;i<5;i++) a += satt[rr][i*16+c]*wor[i];
    hb[flat] += a*sInv[rr];
  }
}

// --------------------------------------------------------------------------
// K4: fused equi_layernorm + MLP + residual.
// --------------------------------------------------------------------------
__global__ __launch_bounds__(256) void k_mlp(
    float* __restrict__ h,
    const float* __restrict__ w1, const float* __restrict__ w2)
{
  __shared__ float sh1[16][10][16];
  int tid = threadIdx.x;
  int c   = tid & 15;
  int tl  = tid >> 4;
  int token = blockIdx.x*16 + tl;
  float* ht = h + (size_t)token*80;
  float hv[5];
  #pragma unroll
  for (int i=0;i<5;i++) hv[i] = ht[i*16 + c];
  bool inner = (0x469D >> c) & 1;
  float part = 0.f;
  if (inner) {
    #pragma unroll
    for (int i=0;i<5;i++) part += hv[i]*hv[i];
  }
  part += __shfl_xor(part, 1);
  part += __shfl_xor(part, 2);
  part += __shfl_xor(part, 4);
  part += __shfl_xor(part, 8);
  float denom = sqrtf(part*(1.f/80.f) + 1e-6f);
  float rinv = 1.f/denom;
  float rln[5];
  #pragma unroll
  for (int i=0;i<5;i++) rln[i] = hv[i]*rinv;

  int g = GRADE16[c];
  #pragma unroll
  for (int o=0;o<10;o++) {
    const float* w1r = w1 + g*50 + o*5;
    float a=0.f;
    #pragma unroll
    for (int i=0;i<5;i++) a += rln[i]*w1r[i];
    sh1[tl][o][c] = a;
  }
  __syncthreads();
  float gpv[5];
  #pragma unroll
  for (int hh=0; hh<5; hh++) {
    float a = 0.f;
    int n = GPT.cnt[c];
    for (int e=0; e<n; ++e) {
      a += GPT.ss[c][e]*sh1[tl][hh][GPT.ii[c][e]]*sh1[tl][5+hh][GPT.jj[c][e]];
    }
    gpv[hh] = a;
  }
  int base = (tid & 63) & ~15;
  #pragma unroll
  for (int hh=0;hh<5;hh++) {
    float g0 = __shfl(gpv[hh], base);
    float u  = 0.7978845608028654f*(g0 + 0.044715f*g0*g0*g0);
    float gate = 0.5f*g0*(1.f + tanhf(u));
    gpv[hh] *= gate;
  }
  #pragma unroll
  for (int o=0;o<5;o++) {
    const float* w2r = w2 + g*25 + o*5;
    float a=0.f;
    #pragma unroll
    for (int i=0;i<5;i++) a += gpv[i]*w2r[i];
    ht[o*16+c] += a;
  }
}

// --------------------------------------------------------------------------
// K5: final equi_linear (w_out) + output extraction.
// --------------------------------------------------------------------------
__global__ __launch_bounds__(256) void k_out(
    const float* __restrict__ h, const float* __restrict__ w_out,
    float* __restrict__ out)
{
  int gid = blockIdx.x*256 + threadIdx.x;
  if (gid >= NTOK*35) return;
  int j = gid % 35, token = gid / 35;
  const float* ht = h + (size_t)token*80;
  float a = 0.f;
  if (j < 32) {
    const float* w = w_out + j*5;              // grade 0, row j
    #pragma unroll
    for (int i=0;i<5;i++) a += ht[i*16 + 0]*w[i];
  } else {
    int c = (j==32)?5:((j==33)?6:8);
    const float* w = w_out + 2*160 + 0*5;      // grade 2, row 0
    #pragma unroll
    for (int i=0;i<5;i++) a += ht[i*16 + c]*w[i];
  }
  out[gid] = a;
}

// --------------------------------------------------------------------------
extern "C" void kernel_launch(void* const* d_in, const int* in_sizes, int n_in,
                              void* d_out, int out_size, void* d_ws, size_t ws_size,
                              hipStream_t stream) {
  const float* x     = (const float*)d_in[0];
  const float* w_in  = (const float*)d_in[1];
  const float* w_out = (const float*)d_in[2];
  const float* wq    = (const float*)d_in[3];
  const float* wk    = (const float*)d_in[4];
  const float* wv    = (const float*)d_in[5];
  const float* wo    = (const float*)d_in[6];
  const float* w1    = (const float*)d_in[7];
  const float* w2    = (const float*)d_in[8];
  float* out = (float*)d_out;

  char* p = (char*)d_ws;
  float* h = (float*)p;              p += (size_t)NTOK*80*4;
  _Float16* qf = (_Float16*)p;       p += (size_t)NTOK*QP*2;
  _Float16* kf = (_Float16*)p;       p += (size_t)NTOK*QP*2;
  _Float16* vf = (_Float16*)p;

  k_init_h<<<(NTOK*5 + 255)/256, 256, 0, stream>>>(x, w_in, h);
  for (int blk=0; blk<3; ++blk) {
    k_ln_qkv<<<NTOK/16, 256, 0, stream>>>(h, wq+blk*125, wk+blk*125, wv+blk*125,
                                          qf, kf, vf);
    k_attn_mfma<<<256, 512, 0, stream>>>(qf, kf, vf, wo+blk*125, h);
    k_mlp<<<NTOK/16, 256, 0, stream>>>(h, w1+blk*250, w2+blk*125);
  }
  k_out<<<(NTOK*35 + 255)/256, 256, 0, stream>>>(h, w_out, out);
}